// Round 16
// baseline (380.187 us; speedup 1.0000x reference)
//
#include <hip/hip_runtime.h>

typedef unsigned short u16;
typedef __bf16 bf16x8 __attribute__((ext_vector_type(8)));
typedef short s16x4 __attribute__((ext_vector_type(4)));
typedef short s16x8 __attribute__((ext_vector_type(8)));
typedef float f32x4 __attribute__((ext_vector_type(4)));

#define S_LEN 2048
#define NHEAD 16
#define QHEAD 192
#define EPS 1e-6f
#define ATTN_SCALE 0.07216878364870323f   /* 192^-0.5 */
#define QSCALE_LOG2E 0.10412011228586118f /* ATTN_SCALE * log2(e) */

__device__ __forceinline__ u16 f2bf(float f) {
    unsigned u = __builtin_bit_cast(unsigned, f);
    u = (u + 0x7FFFu + ((u >> 16) & 1u)) >> 16;
    return (u16)u;
}
__device__ __forceinline__ float bf2f(u16 h) {
    unsigned u = ((unsigned)h) << 16;
    return __builtin_bit_cast(float, u);
}

__device__ __forceinline__ void gl_lds16(const u16* g, u16* l) {
    __builtin_amdgcn_global_load_lds(
        (const __attribute__((address_space(1))) unsigned int*)g,
        (__attribute__((address_space(3))) unsigned int*)l,
        16, 0, 0);
}

#if defined(__has_builtin) && __has_builtin(__builtin_amdgcn_mfma_f32_16x16x16bf16_1k)
__device__ __forceinline__ f32x4 mfma16(s16x4 a, s16x4 b, f32x4 c) {
    return __builtin_amdgcn_mfma_f32_16x16x16bf16_1k(a, b, c, 0, 0, 0);
}
#else
__device__ __forceinline__ f32x4 mfma16(s16x4 a, s16x4 b, f32x4 c) {
    asm volatile("v_mfma_f32_16x16x16_bf16 %0, %1, %2, %0"
                 : "+v"(c) : "v"(a), "v"(b));
    return c;
}
#endif

// ---------------------------------------------------------------------------
// bf16 GEMM core (round-8 counted-vmcnt version, kept from round 15):
// 4-wave blocks, 128x128 tile, wave-tile 64x64, BK=32, triple buffer
// (3 x 16KB = 48KB -> 3 blocks/CU), depth-2 prefetch, counted vmcnt(4).
// ---------------------------------------------------------------------------
template <int CF32>
__device__ __forceinline__ void gemm_core(
    u16* __restrict__ smem,
    const u16* __restrict__ A, const u16* __restrict__ B, void* __restrict__ Cv,
    int K, int lda, int ldb, int ldc, int tm, int tn)
{
    const int tid = threadIdx.x;
    const int w = tid >> 6, lane = tid & 63;
    const int q = lane >> 4, r = lane & 15;

    const int lr = lane & 15;
    const int lc = (lane >> 4) * 8;
    const u16* ga0 = A + (long)(tm * 128 + w * 32 + lr) * lda + lc;
    const u16* ga1 = ga0 + 16 * (long)lda;
    const u16* gb0 = B + (long)(tn * 128 + w * 32 + lr) * ldb + lc;
    const u16* gb1 = gb0 + 16 * (long)ldb;
    const int sa0 = w * 1024, sa1 = sa0 + 512;
    const int sb0 = 4096 + w * 1024, sb1 = sb0 + 512;

    f32x4 acc[4][4] = {};
    const int wm = w >> 1;
    const int wn = w & 1;
    const int n = K >> 5;

    gl_lds16(ga0, smem + sa0);
    gl_lds16(ga1, smem + sa1);
    gl_lds16(gb0, smem + sb0);
    gl_lds16(gb1, smem + sb1);
    gl_lds16(ga0 + 32, smem + 8192 + sa0);
    gl_lds16(ga1 + 32, smem + 8192 + sa1);
    gl_lds16(gb0 + 32, smem + 8192 + sb0);
    gl_lds16(gb1 + 32, smem + 8192 + sb1);
    asm volatile("s_waitcnt vmcnt(4)" ::: "memory");
    __builtin_amdgcn_sched_barrier(0);
    __builtin_amdgcn_s_barrier();
    __builtin_amdgcn_sched_barrier(0);

    int bc = 0;
    for (int t = 0; t < n; ++t) {
        u16* const cur = smem + bc * 8192;
        if (t + 2 < n) {
            int bn = bc + 2; if (bn >= 3) bn -= 3;
            u16* const nxt = smem + bn * 8192;
            const long k2 = (long)(t + 2) << 5;
            gl_lds16(ga0 + k2, nxt + sa0);
            gl_lds16(ga1 + k2, nxt + sa1);
            gl_lds16(gb0 + k2, nxt + sb0);
            gl_lds16(gb1 + k2, nxt + sb1);
        }
        bf16x8 af[4], bv[4];
        #pragma unroll
        for (int mt = 0; mt < 4; ++mt)
            af[mt] = *(const bf16x8*)&cur[(wm * 4 + mt) * 512 + lane * 8];
        #pragma unroll
        for (int nt = 0; nt < 4; ++nt)
            bv[nt] = *(const bf16x8*)&cur[4096 + (wn * 4 + nt) * 512 + lane * 8];
        #pragma unroll
        for (int mt = 0; mt < 4; ++mt)
            #pragma unroll
            for (int nt = 0; nt < 4; ++nt)
                acc[mt][nt] = __builtin_amdgcn_mfma_f32_16x16x32_bf16(
                    af[mt], bv[nt], acc[mt][nt], 0, 0, 0);
        if (t + 1 < n) {
            if (t + 2 < n) asm volatile("s_waitcnt vmcnt(4)" ::: "memory");
            else           asm volatile("s_waitcnt vmcnt(0)" ::: "memory");
            __builtin_amdgcn_sched_barrier(0);
            __builtin_amdgcn_s_barrier();
            __builtin_amdgcn_sched_barrier(0);
        }
        if (++bc == 3) bc = 0;
    }

    const int row0 = tm * 128 + wm * 64 + q * 4;
    const int col0 = tn * 128 + wn * 64 + r;
    if (CF32) {
        float* C = (float*)Cv;
        #pragma unroll
        for (int mt = 0; mt < 4; ++mt)
            #pragma unroll
            for (int i = 0; i < 4; ++i) {
                long rb = (long)(row0 + mt * 16 + i) * ldc + col0;
                #pragma unroll
                for (int nt = 0; nt < 4; ++nt)
                    C[rb + nt * 16] = acc[mt][nt][i];
            }
    } else {
        u16* C = (u16*)Cv;
        #pragma unroll
        for (int mt = 0; mt < 4; ++mt)
            #pragma unroll
            for (int i = 0; i < 4; ++i) {
                long rb = (long)(row0 + mt * 16 + i) * ldc + col0;
                #pragma unroll
                for (int nt = 0; nt < 4; ++nt)
                    C[rb + nt * 16] = f2bf(acc[mt][nt][i]);
            }
    }
}

// fp32 [K][N] -> bf16 [Npad][K] transpose tile body
__device__ __forceinline__ void wtrans_body(
    float (*tile)[33], const float* __restrict__ in, u16* __restrict__ out,
    int K, int N, int bx, int by, int tid)
{
    const int tx = tid & 31, ty = tid >> 5;   // 32 x 8
    const int k0 = bx * 32, n0 = by * 32;
    #pragma unroll
    for (int jj = 0; jj < 32; jj += 8) {
        int nn = n0 + tx;
        tile[ty + jj][tx] = (nn < N) ? in[(long)(k0 + ty + jj) * N + nn] : 0.0f;
    }
    __syncthreads();
    #pragma unroll
    for (int jj = 0; jj < 32; jj += 8)
        out[(long)(n0 + ty + jj) * K + k0 + tx] = f2bf(tile[tx][ty + jj]);
}

// Split-K x2 GEMM: z-slice computes K[z*Kh,(z+1)*Kh) into its own fp32
// partial; consumer sums (norm_k / addout_k).
__global__ __launch_bounds__(256, 2)
void gemm_ks(const u16* __restrict__ A, const u16* __restrict__ B,
             float* __restrict__ C0, float* __restrict__ C1,
             int Kh, int lda, int ldb, int ldc)
{
    __shared__ __align__(16) u16 smem[3 * 8192];
    const int z = blockIdx.z;
    float* C = z ? C1 : C0;
    gemm_core<1>(smem, A + (long)z * Kh, B + (long)z * Kh, C,
                 Kh, lda, ldb, ldc, blockIdx.y, blockIdx.x);
}

// Two independent GEMMs in ONE dispatch (z selects).
__global__ __launch_bounds__(256, 2)
void gemm_bt_dual(const u16* __restrict__ A0, const u16* __restrict__ B0,
                  void* __restrict__ C0, int K0, int lda0, int ldb0, int ldc0, int nx0,
                  const u16* __restrict__ A1, const u16* __restrict__ B1,
                  void* __restrict__ C1, int K1, int lda1, int ldb1, int ldc1, int nx1)
{
    __shared__ __align__(16) u16 smem[3 * 8192];
    if (blockIdx.z == 0) {
        if ((int)blockIdx.x >= nx0) return;
        gemm_core<0>(smem, A0, B0, C0, K0, lda0, ldb0, ldc0,
                     blockIdx.y, blockIdx.x);
    } else {
        if ((int)blockIdx.x >= nx1) return;
        gemm_core<0>(smem, A1, B1, C1, K1, lda1, ldb1, ldc1,
                     blockIdx.y, blockIdx.x);
    }
}

// out[i] += p[i]  (fp32 split-K merge for the final GEMM)
__global__ __launch_bounds__(256)
void addout_k(float4* __restrict__ out, const float4* __restrict__ p)
{
    int i = blockIdx.x * 256 + threadIdx.x;
    float4 a = out[i], b = p[i];
    a.x += b.x; a.y += b.y; a.z += b.z; a.w += b.w;
    out[i] = a;
}

// ---------------------------------------------------------------------------
// Flash attention, S^T form, kv-tile 32, kv-split x2, 4 BLOCKS/CU.
// Round-15 post-mortem: flash occupancy 13% of 25% cap; r1/r8 show flash
// time ~inverse in resident waves. r13's kv-split failed AT 2 blocks/CU
// (grid 1024 > capacity 512; partial-HBM cost uncompensated). Fix both:
// kv-tile 32 -> double-buffer 2 x 20KB = 40KB -> 4 blocks/CU capacity;
// kv-split x2 -> grid 1024 fills it. Chain j+1 <= 32 half-size tiles,
// halves exactly balanced. maskT on the last TWO 32-tiles (t >= ntk-2).
// vt s-permute is per-32-block so kv-32 aligns natively; PV is the sc=0
// slice of the proven kv-64 indexing. Maxless softmax: exact merge
// O=OA+OB, l=lA+lB (merge_k). fp32 partials in dead workspace regions.
// T5 setprio around tile compute. Complementary pairing within each half.
// ---------------------------------------------------------------------------
template<int C0, int C1>
__device__ __forceinline__ void stage_tile32(
    const u16* __restrict__ kvb, const u16* __restrict__ kpe,
    const u16* __restrict__ vt,
    u16* __restrict__ Kl, u16* __restrict__ Vl,
    int h, int t, int quad, int r)
{
    #pragma unroll
    for (int c = C0; c < C1; ++c) {
        if (c < 12) {
            const int mtk = c / 6, kc = c % 6;
            const int row = t * 32 + mtk * 16 + r;
            const u16* src = (kc < 4)
                ? kvb + (size_t)row * 4096 + h * 256 + kc * 32 + quad * 8
                : kpe + (size_t)row * 64 + (kc - 4) * 32 + quad * 8;
            gl_lds16(src, &Kl[c * 512]);
        } else {
            const int mtd = c - 12;
            const u16* src = vt + ((size_t)h * 128 + mtd * 16 + r) * 2048
                             + t * 32 + quad * 8;
            gl_lds16(src, &Vl[mtd * 512]);
        }
    }
}

__device__ __forceinline__ void stage_dispatch32(
    const u16* __restrict__ kvb, const u16* __restrict__ kpe,
    const u16* __restrict__ vt,
    u16* __restrict__ Kl, u16* __restrict__ Vl,
    int w, int h, int t, int quad, int r)
{
    if (w == 0)      stage_tile32<0, 5>(kvb, kpe, vt, Kl, Vl, h, t, quad, r);
    else if (w == 1) stage_tile32<5, 10>(kvb, kpe, vt, Kl, Vl, h, t, quad, r);
    else if (w == 2) stage_tile32<10, 15>(kvb, kpe, vt, Kl, Vl, h, t, quad, r);
    else             stage_tile32<15, 20>(kvb, kpe, vt, Kl, Vl, h, t, quad, r);
}

__device__ __forceinline__ void kv_tile_step32(
    const u16* __restrict__ Kl, const u16* __restrict__ Vl,
    const bf16x8 (&Qf)[6], f32x4 (&Oacc)[8], float& lsum,
    int lane, int quad, int r, int kglob0, int qg, bool maskT)
{
    __builtin_amdgcn_s_setprio(1);
    f32x4 Sacc[2];
    Sacc[0] = (f32x4){0.f, 0.f, 0.f, 0.f};
    Sacc[1] = (f32x4){0.f, 0.f, 0.f, 0.f};
    #pragma unroll
    for (int kc = 0; kc < 6; ++kc)
        #pragma unroll
        for (int mtk = 0; mtk < 2; ++mtk) {
            bf16x8 Ak = *(const bf16x8*)&Kl[(mtk * 6 + kc) * 512 + lane * 8];
            Sacc[mtk] = __builtin_amdgcn_mfma_f32_16x16x32_bf16(
                Ak, Qf[kc], Sacc[mtk], 0, 0, 0);
        }
    s16x4 Pf[2];
    #pragma unroll
    for (int kb = 0; kb < 2; ++kb) {
        const int kb0 = kglob0 + kb * 16 + quad * 4;
        #pragma unroll
        for (int i = 0; i < 4; ++i) {
            float pv = exp2f(Sacc[kb][i]);
            if (maskT && (kb0 + i > qg)) pv = 0.f;
            lsum += pv;
            Pf[kb][i] = (short)f2bf(pv);
        }
    }
    #pragma unroll
    for (int mtd = 0; mtd < 8; ++mtd) {
        s16x8 Av8 = *(const s16x8*)&Vl[mtd * 512 + quad * 128 + r * 8];
        s16x4 lo = __builtin_shufflevector(Av8, Av8, 0, 1, 2, 3);
        s16x4 hi = __builtin_shufflevector(Av8, Av8, 4, 5, 6, 7);
        Oacc[mtd] = mfma16(lo, Pf[0], Oacc[mtd]);
        Oacc[mtd] = mfma16(hi, Pf[1], Oacc[mtd]);
    }
    __builtin_amdgcn_s_setprio(0);
}

__global__ __launch_bounds__(256, 4)
void flash_attn(const u16* __restrict__ query, const u16* __restrict__ kvb,
                const u16* __restrict__ kpe, const u16* __restrict__ vt,
                float* __restrict__ PA, float* __restrict__ PB,
                float* __restrict__ lp)
{
    const int tid = threadIdx.x;
    const int w = tid >> 6, lane = tid & 63;
    const int quad = lane >> 4, r = lane & 15;

    const int bid = (int)blockIdx.x;
    const int hf = bid >> 9;          // kv half
    const int p = bid & 511;          // (j,h) pair, complementary mapping
    const int i = p & 255;
    const int t_ = i >> 4;
    const int h = i & 15;
    const int j = (p < 256) ? (31 - t_) : t_;

    const int q0 = j * 64;
    const int ntk = 2 * (j + 1);          // 32-wide kv tiles to the diagonal
    const int sp = j + 1;                 // balanced split point
    const int t0 = hf ? sp : 0;
    const int t1 = hf ? ntk : sp;

    __shared__ __align__(16) u16 smem[20480];   // 40KB: two 20KB tile buffers
    // buffer b at smem + b*10240: K = [0,6144) u16, V = [6144,10240) u16

    const int qg = q0 + w * 16 + r;

    bf16x8 Qf[6];
    #pragma unroll
    for (int kc = 0; kc < 6; ++kc)
        Qf[kc] = *(const bf16x8*)(query
            + ((size_t)h * S_LEN + q0 + w * 16 + r) * QHEAD
            + kc * 32 + quad * 8);

    f32x4 Oacc[8];
    #pragma unroll
    for (int mtd = 0; mtd < 8; ++mtd)
        Oacc[mtd] = (f32x4){0.f, 0.f, 0.f, 0.f};
    float lsum = 0.f;

    // prologue: stage tile t0 into buffer 0
    stage_dispatch32(kvb, kpe, vt, smem, smem + 6144, w, h, t0, quad, r);
    __syncthreads();

    for (int t = t0; t < t1; ++t) {
        u16* const curb = smem + ((t - t0) & 1) * 10240;       // offset arith,
        u16* const nxtb = smem + ((t - t0 + 1) & 1) * 10240;   // no ptr select
        if (t + 1 < t1)
            stage_dispatch32(kvb, kpe, vt, nxtb, nxtb + 6144, w, h, t + 1, quad, r);
        kv_tile_step32(curb, curb + 6144, Qf, Oacc, lsum,
                       lane, quad, r, t * 32, qg, t >= ntk - 2);
        __syncthreads();
    }

    // epilogue: quad-reduce lsum, write fp32 partials
    float l = lsum;
    l += __shfl_xor(l, 16, 64);
    l += __shfl_xor(l, 32, 64);
    float* OP = hf ? PB : PA;
    const long pb = ((long)p * 64 + w * 16 + r) * 128;
    #pragma unroll
    for (int mtd = 0; mtd < 8; ++mtd)
        *(f32x4*)&OP[pb + mtd * 16 + quad * 4] = Oacc[mtd];
    if (quad == 0)
        lp[hf * 32768 + p * 64 + w * 16 + r] = l;
}

// Merge the two kv-half partials: ao = (OA + OB) / (lA + lB), bf16.
__global__ __launch_bounds__(256)
void merge_k(const float* __restrict__ PA, const float* __restrict__ PB,
             const float* __restrict__ lp, u16* __restrict__ ao)
{
    const int p = (int)blockIdx.x, tid = threadIdx.x;
    const int i = p & 255;
    const int t_ = i >> 4;
    const int h = i & 15;
    const int j = (p < 256) ? (31 - t_) : t_;
    const int q0 = j * 64;
    const int row = tid >> 2;           // 0..63
    const int cseg = (tid & 3) * 32;    // 32-col segment
    const float lA = lp[p * 64 + row];
    const float lB = lp[32768 + p * 64 + row];
    const float inv = 1.0f / (lA + lB);
    const long base = ((long)p * 64 + row) * 128 + cseg;
    u16* dst = ao + (size_t)(q0 + row) * 2048 + h * 128 + cseg;
    #pragma unroll
    for (int k = 0; k < 8; ++k) {
        f32x4 va = *(const f32x4*)&PA[base + k * 4];
        f32x4 vb = *(const f32x4*)&PB[base + k * 4];
        ushort4 o;
        o.x = f2bf((va[0] + vb[0]) * inv);
        o.y = f2bf((va[1] + vb[1]) * inv);
        o.z = f2bf((va[2] + vb[2]) * inv);
        o.w = f2bf((va[3] + vb[3]) * inv);
        *(ushort4*)(dst + k * 4) = o;
    }
}

// ---------------------------------------------------------------------------
// prep_k: fused input-convert + ALL 5 weight transposes (19200 blocks).
// ---------------------------------------------------------------------------
__global__ __launch_bounds__(256)
void prep_k(const float4* __restrict__ x4, ushort4* __restrict__ xb4,
            const float* __restrict__ q_a_w, const float* __restrict__ kv_a_w,
            const float* __restrict__ q_b_w, const float* __restrict__ kv_b_w,
            const float* __restrict__ o_w,
            u16* __restrict__ W1, u16* __restrict__ qbwt,
            u16* __restrict__ kvbwt, u16* __restrict__ owt)
{
    __shared__ float tile[32][33];
    const int tid = threadIdx.x;
    int b = (int)blockIdx.x;
    if (b < 4096) {
        int i = b * 256 + tid;
        float4 v = x4[i];
        ushort4 o;
        o.x = f2bf(v.x); o.y = f2bf(v.y); o.z = f2bf(v.z); o.w = f2bf(v.w);
        xb4[i] = o;
        return;
    }
    b -= 4096;
    if (b < 3072)       wtrans_body(tile, q_a_w,  W1,                  2048, 1536, b % 64, b / 64, tid);
    else if ((b -= 3072) < 1280) wtrans_body(tile, kv_a_w, W1 + 1536ULL * 2048, 2048, 576,  b % 64, b / 64, tid);
    else if ((b -= 1280) < 4608) wtrans_body(tile, q_b_w,  qbwt,       1536, 3072, b % 48, b / 48, tid);
    else if ((b -= 4608) < 2048) wtrans_body(tile, kv_b_w, kvbwt,      512,  4096, b % 16, b / 16, tid);
    else { b -= 2048;            wtrans_body(tile, o_w,    owt,        2048, 2048, b % 64, b / 64, tid); }
}

// ---------------------------------------------------------------------------
// norm_k: split-K merge for gemm1 + q_a rmsnorm + kv_a norm/rope/cache.
// ---------------------------------------------------------------------------
__global__ __launch_bounds__(256)
void norm_k(const float* __restrict__ pa, const float* __restrict__ pb,
            u16* __restrict__ qkv, const float* __restrict__ q_ln,
            const float* __restrict__ kv_ln, const int* __restrict__ pos_ids,
            const float* __restrict__ cosb, const float* __restrict__ sinb,
            float* __restrict__ kvout, u16* __restrict__ cnb,
            u16* __restrict__ kpe)
{
    const int s = blockIdx.x, tid = threadIdx.x;
    __shared__ float rowbuf[2176];
    __shared__ float red[8];
    const long base = (long)s * 2176;
    float sum1 = 0.f, sum2 = 0.f;
    for (int d = tid; d < 2176; d += 256) {
        float v = pa[base + d] + pb[base + d];
        rowbuf[d] = v;
        if (d < 1536)      sum1 += v * v;
        else if (d < 2048) sum2 += v * v;
    }
    #pragma unroll
    for (int o = 32; o; o >>= 1) {
        sum1 += __shfl_xor(sum1, o, 64);
        sum2 += __shfl_xor(sum2, o, 64);
    }
    if ((tid & 63) == 0) { red[tid >> 6] = sum1; red[4 + (tid >> 6)] = sum2; }
    __syncthreads();
    sum1 = red[0] + red[1] + red[2] + red[3];
    sum2 = red[4] + red[5] + red[6] + red[7];
    const float sc1 = rsqrtf(sum1 / 1536.f + EPS);
    const float sc2 = rsqrtf(sum2 / 512.f + EPS);
    for (int d = tid; d < 1536; d += 256)
        qkv[base + d] = f2bf(rowbuf[d] * sc1 * q_ln[d]);
    for (int d = tid; d < 512; d += 256) {
        float v = rowbuf[1536 + d] * sc2 * kv_ln[d];
        kvout[(long)s * 576 + d] = v;
        cnb[(long)s * 512 + d] = f2bf(v);
    }
    if (tid < 32) {
        int p = pos_ids[s];
        float x0 = rowbuf[2048 + 2 * tid];
        float x1 = rowbuf[2048 + 2 * tid + 1];
        float c1 = cosb[p * 64 + tid], s1 = sinb[p * 64 + tid];
        float c2 = cosb[p * 64 + 32 + tid], s2 = sinb[p * 64 + 32 + tid];
        float lo = x0 * c1 - x1 * s1;
        float hi = x1 * c2 + x0 * s2;
        kvout[(long)s * 576 + 512 + tid] = lo;
        kvout[(long)s * 576 + 544 + tid] = hi;
        kpe[(long)s * 64 + tid] = f2bf(lo);
        kpe[(long)s * 64 + 32 + tid] = f2bf(hi);
    }
}

// ---------------------------------------------------------------------------
// post_k: fused qrope ([0,2048) blocks) + vtrans ([2048,6144) blocks).
// vtrans s-axis permuted within 32-blocks so flash PV reads b128.
// ---------------------------------------------------------------------------
__global__ __launch_bounds__(256)
void post_k(const u16* __restrict__ qb, const int* __restrict__ pos_ids,
            const float* __restrict__ cosb, const float* __restrict__ sinb,
            u16* __restrict__ query, const u16* __restrict__ kv,
            u16* __restrict__ vt)
{
    __shared__ u16 tile[32][33];
    const int tid = threadIdx.x;
    int b = (int)blockIdx.x;
    if (b < 2048) {
        const int s = b;
        const u16* row = qb + (long)s * 3072;
        {
            int h = tid >> 4, c = tid & 15;
            const u16* src = &row[h * QHEAD + c * 8];
            u16* dst = &query[((long)(h * S_LEN + s)) * QHEAD + c * 8];
            ushort4 a = *(const ushort4*)src;
            ushort4 bb = *(const ushort4*)(src + 4);
            ushort4 oa, ob;
            oa.x = f2bf(bf2f(a.x) * QSCALE_LOG2E); oa.y = f2bf(bf2f(a.y) * QSCALE_LOG2E);
            oa.z = f2bf(bf2f(a.z) * QSCALE_LOG2E); oa.w = f2bf(bf2f(a.w) * QSCALE_LOG2E);
            ob.x = f2bf(bf2f(bb.x) * QSCALE_LOG2E); ob.y = f2bf(bf2f(bb.y) * QSCALE_LOG2E);
            ob.z = f2bf(bf2f(bb.z) * QSCALE_LOG2E); ob.w = f2bf(bf2f(bb.w) * QSCALE_LOG2E);
            *(ushort4*)dst = oa;
            *(ushort4*)(dst + 4) = ob;
        }
        int p = pos_ids[s];
        for (int idx = tid; idx < 512; idx += 256) {
            int h = idx >> 5, i = idx & 31;
            float x0 = bf2f(row[h * QHEAD + 128 + 2 * i]);
            float x1 = bf2f(row[h * QHEAD + 128 + 2 * i + 1]);
            float c1 = cosb[p * 64 + i], s1 = sinb[p * 64 + i];
            float c2 = cosb[p * 64 + 32 + i], s2 = sinb[p * 64 + 32 + i];
            u16* qr = query + ((long)(h * S_LEN + s)) * QHEAD;
            qr[128 + i] = f2bf((x0 * c1 - x1 * s1) * QSCALE_LOG2E);
            qr[160 + i] = f2bf((x1 * c2 + x0 * s2) * QSCALE_LOG2E);
        }
    } else {
        b -= 2048;
        const int s0 = (b & 63) * 32, d0 = ((b >> 6) & 3) * 32, h = b >> 8;
        const int tx = tid & 31, ty = tid >> 5;
        #pragma unroll
        for (int jj = 0; jj < 32; jj += 8)
            tile[ty + jj][tx] = kv[(long)(s0 + ty + jj) * 4096 + h * 256 + 128 + d0 + tx];
        __syncthreads();
        const int txp = ((tx >> 2) & 3) * 8 + (tx >> 4) * 4 + (tx & 3);
        #pragma unroll
        for (int jj = 0; jj < 32; jj += 8)
            vt[(long)(h * 128 + d0 + ty + jj) * S_LEN + s0 + txp] = tile[tx][ty + jj];
    }
}

// ---------------------------------------------------------------------------
extern "C" void kernel_launch(void* const* d_in, const int* in_sizes, int n_in,
                              void* d_out, int out_size, void* d_ws, size_t ws_size,
                              hipStream_t stream)
{
    const float* x      = (const float*)d_in[0];
    const int*   posid  = (const int*)d_in[2];
    const float* cosb   = (const float*)d_in[3];
    const float* sinb   = (const float*)d_in[4];
    const float* q_a_w  = (const float*)d_in[5];
    const float* q_a_ln = (const float*)d_in[6];
    const float* q_b_w  = (const float*)d_in[7];
    const float* kv_a_w = (const float*)d_in[8];
    const float* kv_a_ln= (const float*)d_in[9];
    const float* kv_b_w = (const float*)d_in[10];
    const float* o_w    = (const float*)d_in[11];

    float* out    = (float*)d_out;
    float* kv_out = out + (size_t)2048 * 2048;

    char* ws = (char*)d_ws;
    size_t off = 0;
    auto alloc = [&](size_t bytes) { char* p = ws + off; off += (bytes + 255) & ~(size_t)255; return p; };
    // owt BEFORE qbwt so that qbwt..qkv_a is a contiguous dead-after-dual
    // span (22.5MB) for flash partial PB.
    u16* xb    = (u16*)alloc(2048ULL * 2048 * 2);   // 8.4MB
    u16* W1    = (u16*)alloc(2176ULL * 2048 * 2);   // 8.9MB  [q_a^T; kv_a^T]
    u16* owt   = (u16*)alloc(2048ULL * 2048 * 2);   // 8.4MB
    u16* qbwt  = (u16*)alloc(3072ULL * 1536 * 2);   // 9.4MB
    u16* kvbwt = (u16*)alloc(4096ULL * 512 * 2);    // 4.2MB
    u16* qkv_a = (u16*)alloc(2048ULL * 2176 * 2);   // 8.9MB [q_a_norm(1536)|-]
    u16* qbuf  = (u16*)alloc(2048ULL * 3072 * 2);   // 12.6MB
    u16* query = (u16*)alloc(16ULL * 2048 * 192 * 2);
    u16* cnb   = (u16*)alloc(2048ULL * 512 * 2);
    u16* kpe   = (u16*)alloc(2048ULL * 64 * 2);
    u16* kvbuf = (u16*)alloc(2048ULL * 4096 * 2);
    u16* vt    = (u16*)alloc(16ULL * 128 * 2048 * 2);
    u16* ao    = (u16*)alloc(2048ULL * 2048 * 2);
    (void)ws_size; (void)in_sizes; (void)n_in; (void)out_size;

    // Overlays (sequential reuse of dead regions, all proven in r13):
    //  g1p0/g1p1: gemm1 fp32 partials (17.8MB) on qbuf+query / kvbuf+vt
    //    (consumed by norm_k before dual/post write those regions).
    //  PA: flash half-A partials (16.78MB) on xb+W1 (dead after gemm1).
    //  PB: flash half-B partials on qbwt+kvbwt+qkv_a (22.5MB, dead after dual).
    //  lp: per-row lsums (256KB) on cnb (dead after dual).
    //  g5p: gemm5 partial (16.8MB) on xb+W1 AFTER merge_k consumed PA.
    float* g1p0 = (float*)qbuf;
    float* g1p1 = (float*)kvbuf;
    float* PA   = (float*)xb;
    float* PB   = (float*)qbwt;
    float* lp   = (float*)cnb;
    float* g5p  = (float*)xb;

    dim3 blk(256);

    // 0) fused input cvt + all weight transposes (19200 blocks)
    prep_k<<<dim3(19200), blk, 0, stream>>>(
        (const float4*)x, (ushort4*)xb, q_a_w, kv_a_w, q_b_w, kv_b_w, o_w,
        W1, qbwt, kvbwt, owt);

    // 1) gemm1 split-K x2 (544 blocks)
    gemm_ks<<<dim3(17, 16, 2), blk, 0, stream>>>(
        xb, W1, g1p0, g1p1, 1024, 2048, 2048, 2176);

    // 2) split-K merge + rmsnorm + kv norm/rope/cache
    norm_k<<<dim3(2048), blk, 0, stream>>>(g1p0, g1p1, qkv_a, q_a_ln, kv_a_ln,
                                           posid, cosb, sinb, kv_out, cnb, kpe);

    // 3) q = q_a_norm @ q_b_w  AND  kv = c_norm @ kv_b_w  (one dispatch)
    gemm_bt_dual<<<dim3(32, 16, 2), blk, 0, stream>>>(
        qkv_a, qbwt, qbuf, 1536, 2176, 1536, 3072, 24,
        cnb, kvbwt, kvbuf, 512, 512, 512, 4096, 32);

    // 4) fused qrope + value transpose
    post_k<<<dim3(6144), blk, 0, stream>>>(qbuf, posid, cosb, sinb, query, kvbuf, vt);

    // 5) flash attention, kv-tile 32, kv-split x2, 4 blocks/CU (1024 blocks)
    flash_attn<<<dim3(1024), blk, 0, stream>>>(query, kvbuf, kpe, vt, PA, PB, lp);

    // 6) merge halves -> ao bf16 [S][H*128]
    merge_k<<<dim3(512), blk, 0, stream>>>(PA, PB, lp, ao);

    // 7) out = ao @ o_w (fp32), split-K x2; then out += g5p
    gemm_ks<<<dim3(16, 16, 2), blk, 0, stream>>>(
        ao, owt, g5p, out, 1024, 2048, 2048, 2048);
    addout_k<<<dim3(4096), blk, 0, stream>>>((float4*)out, (const float4*)g5p);
}

// Round 17
// 371.388 us; speedup vs baseline: 1.0237x; 1.0237x over previous
//
#include <hip/hip_runtime.h>

typedef unsigned short u16;
typedef __bf16 bf16x8 __attribute__((ext_vector_type(8)));
typedef short s16x4 __attribute__((ext_vector_type(4)));
typedef short s16x8 __attribute__((ext_vector_type(8)));
typedef float f32x4 __attribute__((ext_vector_type(4)));

#define S_LEN 2048
#define NHEAD 16
#define QHEAD 192
#define EPS 1e-6f
#define ATTN_SCALE 0.07216878364870323f   /* 192^-0.5 */
#define QSCALE_LOG2E 0.10412011228586118f /* ATTN_SCALE * log2(e) */

__device__ __forceinline__ u16 f2bf(float f) {
    unsigned u = __builtin_bit_cast(unsigned, f);
    u = (u + 0x7FFFu + ((u >> 16) & 1u)) >> 16;
    return (u16)u;
}
__device__ __forceinline__ float bf2f(u16 h) {
    unsigned u = ((unsigned)h) << 16;
    return __builtin_bit_cast(float, u);
}

__device__ __forceinline__ void gl_lds16(const u16* g, u16* l) {
    __builtin_amdgcn_global_load_lds(
        (const __attribute__((address_space(1))) unsigned int*)g,
        (__attribute__((address_space(3))) unsigned int*)l,
        16, 0, 0);
}

#if defined(__has_builtin) && __has_builtin(__builtin_amdgcn_mfma_f32_16x16x16bf16_1k)
__device__ __forceinline__ f32x4 mfma16(s16x4 a, s16x4 b, f32x4 c) {
    return __builtin_amdgcn_mfma_f32_16x16x16bf16_1k(a, b, c, 0, 0, 0);
}
#else
__device__ __forceinline__ f32x4 mfma16(s16x4 a, s16x4 b, f32x4 c) {
    asm volatile("v_mfma_f32_16x16x16_bf16 %0, %1, %2, %0"
                 : "+v"(c) : "v"(a), "v"(b));
    return c;
}
#endif

// ---------------------------------------------------------------------------
// bf16 GEMM core (round-8 counted-vmcnt version): 4-wave blocks, 128x128
// tile, wave-tile 64x64, BK=32, triple buffer (3 x 16KB = 48KB -> 3
// blocks/CU), depth-2 prefetch, counted vmcnt(4). Best measured GEMM core
// (r15: dual 71.1us, occupancy 22%).
// ---------------------------------------------------------------------------
template <int CF32>
__device__ __forceinline__ void gemm_core(
    u16* __restrict__ smem,
    const u16* __restrict__ A, const u16* __restrict__ B, void* __restrict__ Cv,
    int K, int lda, int ldb, int ldc, int tm, int tn)
{
    const int tid = threadIdx.x;
    const int w = tid >> 6, lane = tid & 63;
    const int q = lane >> 4, r = lane & 15;

    const int lr = lane & 15;
    const int lc = (lane >> 4) * 8;
    const u16* ga0 = A + (long)(tm * 128 + w * 32 + lr) * lda + lc;
    const u16* ga1 = ga0 + 16 * (long)lda;
    const u16* gb0 = B + (long)(tn * 128 + w * 32 + lr) * ldb + lc;
    const u16* gb1 = gb0 + 16 * (long)ldb;
    const int sa0 = w * 1024, sa1 = sa0 + 512;
    const int sb0 = 4096 + w * 1024, sb1 = sb0 + 512;

    f32x4 acc[4][4] = {};
    const int wm = w >> 1;
    const int wn = w & 1;
    const int n = K >> 5;

    gl_lds16(ga0, smem + sa0);
    gl_lds16(ga1, smem + sa1);
    gl_lds16(gb0, smem + sb0);
    gl_lds16(gb1, smem + sb1);
    gl_lds16(ga0 + 32, smem + 8192 + sa0);
    gl_lds16(ga1 + 32, smem + 8192 + sa1);
    gl_lds16(gb0 + 32, smem + 8192 + sb0);
    gl_lds16(gb1 + 32, smem + 8192 + sb1);
    asm volatile("s_waitcnt vmcnt(4)" ::: "memory");
    __builtin_amdgcn_sched_barrier(0);
    __builtin_amdgcn_s_barrier();
    __builtin_amdgcn_sched_barrier(0);

    int bc = 0;
    for (int t = 0; t < n; ++t) {
        u16* const cur = smem + bc * 8192;
        if (t + 2 < n) {
            int bn = bc + 2; if (bn >= 3) bn -= 3;
            u16* const nxt = smem + bn * 8192;
            const long k2 = (long)(t + 2) << 5;
            gl_lds16(ga0 + k2, nxt + sa0);
            gl_lds16(ga1 + k2, nxt + sa1);
            gl_lds16(gb0 + k2, nxt + sb0);
            gl_lds16(gb1 + k2, nxt + sb1);
        }
        bf16x8 af[4], bv[4];
        #pragma unroll
        for (int mt = 0; mt < 4; ++mt)
            af[mt] = *(const bf16x8*)&cur[(wm * 4 + mt) * 512 + lane * 8];
        #pragma unroll
        for (int nt = 0; nt < 4; ++nt)
            bv[nt] = *(const bf16x8*)&cur[4096 + (wn * 4 + nt) * 512 + lane * 8];
        #pragma unroll
        for (int mt = 0; mt < 4; ++mt)
            #pragma unroll
            for (int nt = 0; nt < 4; ++nt)
                acc[mt][nt] = __builtin_amdgcn_mfma_f32_16x16x32_bf16(
                    af[mt], bv[nt], acc[mt][nt], 0, 0, 0);
        if (t + 1 < n) {
            if (t + 2 < n) asm volatile("s_waitcnt vmcnt(4)" ::: "memory");
            else           asm volatile("s_waitcnt vmcnt(0)" ::: "memory");
            __builtin_amdgcn_sched_barrier(0);
            __builtin_amdgcn_s_barrier();
            __builtin_amdgcn_sched_barrier(0);
        }
        if (++bc == 3) bc = 0;
    }

    const int row0 = tm * 128 + wm * 64 + q * 4;
    const int col0 = tn * 128 + wn * 64 + r;
    if (CF32) {
        float* C = (float*)Cv;
        #pragma unroll
        for (int mt = 0; mt < 4; ++mt)
            #pragma unroll
            for (int i = 0; i < 4; ++i) {
                long rb = (long)(row0 + mt * 16 + i) * ldc + col0;
                #pragma unroll
                for (int nt = 0; nt < 4; ++nt)
                    C[rb + nt * 16] = acc[mt][nt][i];
            }
    } else {
        u16* C = (u16*)Cv;
        #pragma unroll
        for (int mt = 0; mt < 4; ++mt)
            #pragma unroll
            for (int i = 0; i < 4; ++i) {
                long rb = (long)(row0 + mt * 16 + i) * ldc + col0;
                #pragma unroll
                for (int nt = 0; nt < 4; ++nt)
                    C[rb + nt * 16] = f2bf(acc[mt][nt][i]);
            }
    }
}

// fp32 [K][N] -> bf16 [Npad][K] transpose tile body
__device__ __forceinline__ void wtrans_body(
    float (*tile)[33], const float* __restrict__ in, u16* __restrict__ out,
    int K, int N, int bx, int by, int tid)
{
    const int tx = tid & 31, ty = tid >> 5;   // 32 x 8
    const int k0 = bx * 32, n0 = by * 32;
    #pragma unroll
    for (int jj = 0; jj < 32; jj += 8) {
        int nn = n0 + tx;
        tile[ty + jj][tx] = (nn < N) ? in[(long)(k0 + ty + jj) * N + nn] : 0.0f;
    }
    __syncthreads();
    #pragma unroll
    for (int jj = 0; jj < 32; jj += 8)
        out[(long)(n0 + ty + jj) * K + k0 + tx] = f2bf(tile[tx][ty + jj]);
}

// Split-K x2 GEMM: z-slice computes K[z*Kh,(z+1)*Kh) into its own fp32
// partial; consumer sums (norm_k / addout_k).
__global__ __launch_bounds__(256, 2)
void gemm_ks(const u16* __restrict__ A, const u16* __restrict__ B,
             float* __restrict__ C0, float* __restrict__ C1,
             int Kh, int lda, int ldb, int ldc)
{
    __shared__ __align__(16) u16 smem[3 * 8192];
    const int z = blockIdx.z;
    float* C = z ? C1 : C0;
    gemm_core<1>(smem, A + (long)z * Kh, B + (long)z * Kh, C,
                 Kh, lda, ldb, ldc, blockIdx.y, blockIdx.x);
}

// Two independent GEMMs in ONE dispatch (z selects).
__global__ __launch_bounds__(256, 2)
void gemm_bt_dual(const u16* __restrict__ A0, const u16* __restrict__ B0,
                  void* __restrict__ C0, int K0, int lda0, int ldb0, int ldc0, int nx0,
                  const u16* __restrict__ A1, const u16* __restrict__ B1,
                  void* __restrict__ C1, int K1, int lda1, int ldb1, int ldc1, int nx1)
{
    __shared__ __align__(16) u16 smem[3 * 8192];
    if (blockIdx.z == 0) {
        if ((int)blockIdx.x >= nx0) return;
        gemm_core<0>(smem, A0, B0, C0, K0, lda0, ldb0, ldc0,
                     blockIdx.y, blockIdx.x);
    } else {
        if ((int)blockIdx.x >= nx1) return;
        gemm_core<0>(smem, A1, B1, C1, K1, lda1, ldb1, ldc1,
                     blockIdx.y, blockIdx.x);
    }
}

// out[i] += p[i]  (fp32 split-K merge for the final GEMM)
__global__ __launch_bounds__(256)
void addout_k(float4* __restrict__ out, const float4* __restrict__ p)
{
    int i = blockIdx.x * 256 + threadIdx.x;
    float4 a = out[i], b = p[i];
    a.x += b.x; a.y += b.y; a.z += b.z; a.w += b.w;
    out[i] = a;
}

// ---------------------------------------------------------------------------
// Flash attention, S^T form, pipelined - the best measured config (r15):
// 4 waves x 16 q-rows, 256 threads, kv-tile 64, 2x40KB LDS (2 blocks/CU),
// direct ao write, T5 setprio around tile compute. PV reads conflict-free
// b128 via s-permuted vt. Maxless exp2 softmax. Grid 1D 512, complementary
// pairing. Both perturbation directions measured worse: r8 (fewer waves,
// more work/block) +46us; r16 (more waves via kv-32+split) +8us.
// ---------------------------------------------------------------------------
template<int C0, int C1>
__device__ __forceinline__ void stage_tile(
    const u16* __restrict__ kvb, const u16* __restrict__ kpe,
    const u16* __restrict__ vt,
    u16* __restrict__ Kl, u16* __restrict__ Vl,
    int h, int t, int quad, int r)
{
    #pragma unroll
    for (int c = C0; c < C1; ++c) {
        if (c < 24) {
            const int mtk = c / 6, kc = c % 6;
            const int row = t * 64 + mtk * 16 + r;
            const u16* src = (kc < 4)
                ? kvb + (size_t)row * 4096 + h * 256 + kc * 32 + quad * 8
                : kpe + (size_t)row * 64 + (kc - 4) * 32 + quad * 8;
            gl_lds16(src, &Kl[c * 512]);
        } else {
            const int cv = c - 24, mtd = cv >> 1, sc = cv & 1;
            const u16* src = vt + ((size_t)h * 128 + mtd * 16 + r) * 2048
                             + t * 64 + sc * 32 + quad * 8;
            gl_lds16(src, &Vl[cv * 512]);
        }
    }
}

__device__ __forceinline__ void stage_dispatch(
    const u16* __restrict__ kvb, const u16* __restrict__ kpe,
    const u16* __restrict__ vt,
    u16* __restrict__ Kl, u16* __restrict__ Vl,
    int w, int h, int t, int quad, int r)
{
    if (w == 0)      stage_tile<0, 10>(kvb, kpe, vt, Kl, Vl, h, t, quad, r);
    else if (w == 1) stage_tile<10, 20>(kvb, kpe, vt, Kl, Vl, h, t, quad, r);
    else if (w == 2) stage_tile<20, 30>(kvb, kpe, vt, Kl, Vl, h, t, quad, r);
    else             stage_tile<30, 40>(kvb, kpe, vt, Kl, Vl, h, t, quad, r);
}

__device__ __forceinline__ void kv_tile_step(
    const u16* __restrict__ Kl, const u16* __restrict__ Vl,
    const bf16x8 (&Qf)[6], f32x4 (&Oacc)[8], float& lsum,
    int lane, int quad, int r, int kglob0, int qg, bool maskT)
{
    __builtin_amdgcn_s_setprio(1);
    f32x4 Sacc[4];
    #pragma unroll
    for (int mtk = 0; mtk < 4; ++mtk)
        Sacc[mtk] = (f32x4){0.f, 0.f, 0.f, 0.f};
    #pragma unroll
    for (int kc = 0; kc < 6; ++kc)
        #pragma unroll
        for (int mtk = 0; mtk < 4; ++mtk) {
            bf16x8 Ak = *(const bf16x8*)&Kl[(mtk * 6 + kc) * 512 + lane * 8];
            Sacc[mtk] = __builtin_amdgcn_mfma_f32_16x16x32_bf16(
                Ak, Qf[kc], Sacc[mtk], 0, 0, 0);
        }
    #pragma unroll
    for (int sc = 0; sc < 2; ++sc) {
        s16x4 Pf[2];
        #pragma unroll
        for (int half = 0; half < 2; ++half) {
            const int kb = sc * 2 + half;
            const int kb0 = kglob0 + kb * 16 + quad * 4;
            #pragma unroll
            for (int i = 0; i < 4; ++i) {
                float pv = exp2f(Sacc[kb][i]);
                if (maskT && (kb0 + i > qg)) pv = 0.f;
                lsum += pv;
                Pf[half][i] = (short)f2bf(pv);
            }
        }
        #pragma unroll
        for (int mtd = 0; mtd < 8; ++mtd) {
            s16x8 Av8 = *(const s16x8*)&Vl[(mtd * 2 + sc) * 512 + quad * 128 + r * 8];
            s16x4 lo = __builtin_shufflevector(Av8, Av8, 0, 1, 2, 3);
            s16x4 hi = __builtin_shufflevector(Av8, Av8, 4, 5, 6, 7);
            Oacc[mtd] = mfma16(lo, Pf[0], Oacc[mtd]);
            Oacc[mtd] = mfma16(hi, Pf[1], Oacc[mtd]);
        }
    }
    __builtin_amdgcn_s_setprio(0);
}

__global__ __launch_bounds__(256, 2)
void flash_attn(const u16* __restrict__ query, const u16* __restrict__ kvb,
                const u16* __restrict__ kpe, const u16* __restrict__ vt,
                u16* __restrict__ ao)
{
    const int tid = threadIdx.x;
    const int w = tid >> 6, lane = tid & 63;
    const int quad = lane >> 4, r = lane & 15;

    const int bid = (int)blockIdx.x;
    const int i = bid & 255;
    const int t_ = i >> 4;
    const int h = i & 15;
    const int j = (bid < 256) ? (31 - t_) : t_;

    const int q0 = j * 64;
    const int ntk = j + 1;

    __shared__ __align__(16) u16 smem[40960];   // 80KB: two 40KB tile buffers
    // buffer b at smem + b*20480: K = [0,12288) u16, V = [12288,20480) u16

    const int qg = q0 + w * 16 + r;   // this wave's q row (causal bound)

    bf16x8 Qf[6];
    #pragma unroll
    for (int kc = 0; kc < 6; ++kc)
        Qf[kc] = *(const bf16x8*)(query
            + ((size_t)h * S_LEN + q0 + w * 16 + r) * QHEAD
            + kc * 32 + quad * 8);

    f32x4 Oacc[8];
    #pragma unroll
    for (int mtd = 0; mtd < 8; ++mtd)
        Oacc[mtd] = (f32x4){0.f, 0.f, 0.f, 0.f};
    float lsum = 0.f;

    // prologue: stage tile 0 into buffer 0
    stage_dispatch(kvb, kpe, vt, smem, smem + 12288, w, h, 0, quad, r);
    __syncthreads();

    for (int t = 0; t < ntk; ++t) {
        u16* const curb = smem + (t & 1) * 20480;          // offset arith,
        u16* const nxtb = smem + ((t + 1) & 1) * 20480;    // no ptr select
        if (t + 1 < ntk)
            stage_dispatch(kvb, kpe, vt, nxtb, nxtb + 12288, w, h, t + 1, quad, r);
        kv_tile_step(curb, curb + 12288, Qf, Oacc, lsum,
                     lane, quad, r, t * 64, qg, t == ntk - 1);
        __syncthreads();
    }

    // epilogue: each wave owns its 16 q-rows; reduce lsum over quads only
    float l = lsum;
    l += __shfl_xor(l, 16, 64);
    l += __shfl_xor(l, 32, 64);
    const float inv = 1.0f / l;
    const int qrow = q0 + w * 16 + r;
    #pragma unroll
    for (int mtd = 0; mtd < 8; ++mtd) {
        ushort4 o;
        o.x = f2bf(Oacc[mtd][0] * inv);
        o.y = f2bf(Oacc[mtd][1] * inv);
        o.z = f2bf(Oacc[mtd][2] * inv);
        o.w = f2bf(Oacc[mtd][3] * inv);
        *(ushort4*)(ao + (size_t)qrow * 2048 + h * 128 + mtd * 16 + quad * 4) = o;
    }
}

// ---------------------------------------------------------------------------
// prep_k: fused input-convert + ALL 5 weight transposes (19200 blocks).
// ---------------------------------------------------------------------------
__global__ __launch_bounds__(256)
void prep_k(const float4* __restrict__ x4, ushort4* __restrict__ xb4,
            const float* __restrict__ q_a_w, const float* __restrict__ kv_a_w,
            const float* __restrict__ q_b_w, const float* __restrict__ kv_b_w,
            const float* __restrict__ o_w,
            u16* __restrict__ W1, u16* __restrict__ qbwt,
            u16* __restrict__ kvbwt, u16* __restrict__ owt)
{
    __shared__ float tile[32][33];
    const int tid = threadIdx.x;
    int b = (int)blockIdx.x;
    if (b < 4096) {
        int i = b * 256 + tid;
        float4 v = x4[i];
        ushort4 o;
        o.x = f2bf(v.x); o.y = f2bf(v.y); o.z = f2bf(v.z); o.w = f2bf(v.w);
        xb4[i] = o;
        return;
    }
    b -= 4096;
    if (b < 3072)       wtrans_body(tile, q_a_w,  W1,                  2048, 1536, b % 64, b / 64, tid);
    else if ((b -= 3072) < 1280) wtrans_body(tile, kv_a_w, W1 + 1536ULL * 2048, 2048, 576,  b % 64, b / 64, tid);
    else if ((b -= 1280) < 4608) wtrans_body(tile, q_b_w,  qbwt,       1536, 3072, b % 48, b / 48, tid);
    else if ((b -= 4608) < 2048) wtrans_body(tile, kv_b_w, kvbwt,      512,  4096, b % 16, b / 16, tid);
    else { b -= 2048;            wtrans_body(tile, o_w,    owt,        2048, 2048, b % 64, b / 64, tid); }
}

// ---------------------------------------------------------------------------
// norm_k: split-K merge for gemm1 + q_a rmsnorm + kv_a norm/rope/cache.
// ---------------------------------------------------------------------------
__global__ __launch_bounds__(256)
void norm_k(const float* __restrict__ pa, const float* __restrict__ pb,
            u16* __restrict__ qkv, const float* __restrict__ q_ln,
            const float* __restrict__ kv_ln, const int* __restrict__ pos_ids,
            const float* __restrict__ cosb, const float* __restrict__ sinb,
            float* __restrict__ kvout, u16* __restrict__ cnb,
            u16* __restrict__ kpe)
{
    const int s = blockIdx.x, tid = threadIdx.x;
    __shared__ float rowbuf[2176];
    __shared__ float red[8];
    const long base = (long)s * 2176;
    float sum1 = 0.f, sum2 = 0.f;
    for (int d = tid; d < 2176; d += 256) {
        float v = pa[base + d] + pb[base + d];
        rowbuf[d] = v;
        if (d < 1536)      sum1 += v * v;
        else if (d < 2048) sum2 += v * v;
    }
    #pragma unroll
    for (int o = 32; o; o >>= 1) {
        sum1 += __shfl_xor(sum1, o, 64);
        sum2 += __shfl_xor(sum2, o, 64);
    }
    if ((tid & 63) == 0) { red[tid >> 6] = sum1; red[4 + (tid >> 6)] = sum2; }
    __syncthreads();
    sum1 = red[0] + red[1] + red[2] + red[3];
    sum2 = red[4] + red[5] + red[6] + red[7];
    const float sc1 = rsqrtf(sum1 / 1536.f + EPS);
    const float sc2 = rsqrtf(sum2 / 512.f + EPS);
    for (int d = tid; d < 1536; d += 256)
        qkv[base + d] = f2bf(rowbuf[d] * sc1 * q_ln[d]);
    for (int d = tid; d < 512; d += 256) {
        float v = rowbuf[1536 + d] * sc2 * kv_ln[d];
        kvout[(long)s * 576 + d] = v;
        cnb[(long)s * 512 + d] = f2bf(v);
    }
    if (tid < 32) {
        int p = pos_ids[s];
        float x0 = rowbuf[2048 + 2 * tid];
        float x1 = rowbuf[2048 + 2 * tid + 1];
        float c1 = cosb[p * 64 + tid], s1 = sinb[p * 64 + tid];
        float c2 = cosb[p * 64 + 32 + tid], s2 = sinb[p * 64 + 32 + tid];
        float lo = x0 * c1 - x1 * s1;
        float hi = x1 * c2 + x0 * s2;
        kvout[(long)s * 576 + 512 + tid] = lo;
        kvout[(long)s * 576 + 544 + tid] = hi;
        kpe[(long)s * 64 + tid] = f2bf(lo);
        kpe[(long)s * 64 + 32 + tid] = f2bf(hi);
    }
}

// ---------------------------------------------------------------------------
// post_k: fused qrope ([0,2048) blocks) + vtrans ([2048,6144) blocks).
// vtrans s-axis permuted within 32-blocks so flash PV reads b128.
// ---------------------------------------------------------------------------
__global__ __launch_bounds__(256)
void post_k(const u16* __restrict__ qb, const int* __restrict__ pos_ids,
            const float* __restrict__ cosb, const float* __restrict__ sinb,
            u16* __restrict__ query, const u16* __restrict__ kv,
            u16* __restrict__ vt)
{
    __shared__ u16 tile[32][33];
    const int tid = threadIdx.x;
    int b = (int)blockIdx.x;
    if (b < 2048) {
        const int s = b;
        const u16* row = qb + (long)s * 3072;
        {
            int h = tid >> 4, c = tid & 15;
            const u16* src = &row[h * QHEAD + c * 8];
            u16* dst = &query[((long)(h * S_LEN + s)) * QHEAD + c * 8];
            ushort4 a = *(const ushort4*)src;
            ushort4 bb = *(const ushort4*)(src + 4);
            ushort4 oa, ob;
            oa.x = f2bf(bf2f(a.x) * QSCALE_LOG2E); oa.y = f2bf(bf2f(a.y) * QSCALE_LOG2E);
            oa.z = f2bf(bf2f(a.z) * QSCALE_LOG2E); oa.w = f2bf(bf2f(a.w) * QSCALE_LOG2E);
            ob.x = f2bf(bf2f(bb.x) * QSCALE_LOG2E); ob.y = f2bf(bf2f(bb.y) * QSCALE_LOG2E);
            ob.z = f2bf(bf2f(bb.z) * QSCALE_LOG2E); ob.w = f2bf(bf2f(bb.w) * QSCALE_LOG2E);
            *(ushort4*)dst = oa;
            *(ushort4*)(dst + 4) = ob;
        }
        int p = pos_ids[s];
        for (int idx = tid; idx < 512; idx += 256) {
            int h = idx >> 5, i = idx & 31;
            float x0 = bf2f(row[h * QHEAD + 128 + 2 * i]);
            float x1 = bf2f(row[h * QHEAD + 128 + 2 * i + 1]);
            float c1 = cosb[p * 64 + i], s1 = sinb[p * 64 + i];
            float c2 = cosb[p * 64 + 32 + i], s2 = sinb[p * 64 + 32 + i];
            u16* qr = query + ((long)(h * S_LEN + s)) * QHEAD;
            qr[128 + i] = f2bf((x0 * c1 - x1 * s1) * QSCALE_LOG2E);
            qr[160 + i] = f2bf((x1 * c2 + x0 * s2) * QSCALE_LOG2E);
        }
    } else {
        b -= 2048;
        const int s0 = (b & 63) * 32, d0 = ((b >> 6) & 3) * 32, h = b >> 8;
        const int tx = tid & 31, ty = tid >> 5;
        #pragma unroll
        for (int jj = 0; jj < 32; jj += 8)
            tile[ty + jj][tx] = kv[(long)(s0 + ty + jj) * 4096 + h * 256 + 128 + d0 + tx];
        __syncthreads();
        const int txp = ((tx >> 2) & 3) * 8 + (tx >> 4) * 4 + (tx & 3);
        #pragma unroll
        for (int jj = 0; jj < 32; jj += 8)
            vt[(long)(h * 128 + d0 + ty + jj) * S_LEN + s0 + txp] = tile[tx][ty + jj];
    }
}

// ---------------------------------------------------------------------------
extern "C" void kernel_launch(void* const* d_in, const int* in_sizes, int n_in,
                              void* d_out, int out_size, void* d_ws, size_t ws_size,
                              hipStream_t stream)
{
    const float* x      = (const float*)d_in[0];
    const int*   posid  = (const int*)d_in[2];
    const float* cosb   = (const float*)d_in[3];
    const float* sinb   = (const float*)d_in[4];
    const float* q_a_w  = (const float*)d_in[5];
    const float* q_a_ln = (const float*)d_in[6];
    const float* q_b_w  = (const float*)d_in[7];
    const float* kv_a_w = (const float*)d_in[8];
    const float* kv_a_ln= (const float*)d_in[9];
    const float* kv_b_w = (const float*)d_in[10];
    const float* o_w    = (const float*)d_in[11];

    float* out    = (float*)d_out;
    float* kv_out = out + (size_t)2048 * 2048;

    char* ws = (char*)d_ws;
    size_t off = 0;
    auto alloc = [&](size_t bytes) { char* p = ws + off; off += (bytes + 255) & ~(size_t)255; return p; };
    u16* xb    = (u16*)alloc(2048ULL * 2048 * 2);   // 8.4MB
    u16* W1    = (u16*)alloc(2176ULL * 2048 * 2);   // 8.9MB  [q_a^T; kv_a^T]
    u16* owt   = (u16*)alloc(2048ULL * 2048 * 2);   // 8.4MB
    u16* qbwt  = (u16*)alloc(3072ULL * 1536 * 2);   // 9.4MB
    u16* kvbwt = (u16*)alloc(4096ULL * 512 * 2);    // 4.2MB
    u16* qkv_a = (u16*)alloc(2048ULL * 2176 * 2);   // 8.9MB [q_a_norm(1536)|-]
    u16* qbuf  = (u16*)alloc(2048ULL * 3072 * 2);   // 12.6MB
    u16* query = (u16*)alloc(16ULL * 2048 * 192 * 2);
    u16* cnb   = (u16*)alloc(2048ULL * 512 * 2);
    u16* kpe   = (u16*)alloc(2048ULL * 64 * 2);
    u16* kvbuf = (u16*)alloc(2048ULL * 4096 * 2);
    u16* vt    = (u16*)alloc(16ULL * 128 * 2048 * 2);
    u16* ao    = (u16*)alloc(2048ULL * 2048 * 2);
    (void)ws_size; (void)in_sizes; (void)n_in; (void)out_size;

    // Overlays (sequential reuse of dead regions):
    //  g1p0/g1p1: gemm1 fp32 partials (17.8MB) on qbuf+query / kvbuf+vt
    //    (consumed by norm_k before dual/post write those regions).
    //  g5p: gemm5 partial (16.8MB) on xb+W1 (dead after gemm1).
    float* g1p0 = (float*)qbuf;
    float* g1p1 = (float*)kvbuf;
    float* g5p  = (float*)xb;

    dim3 blk(256);

    // 0) fused input cvt + all weight transposes (19200 blocks)
    prep_k<<<dim3(19200), blk, 0, stream>>>(
        (const float4*)x, (ushort4*)xb, q_a_w, kv_a_w, q_b_w, kv_b_w, o_w,
        W1, qbwt, kvbwt, owt);

    // 1) gemm1 split-K x2 (544 blocks)
    gemm_ks<<<dim3(17, 16, 2), blk, 0, stream>>>(
        xb, W1, g1p0, g1p1, 1024, 2048, 2048, 2176);

    // 2) split-K merge + rmsnorm + kv norm/rope/cache
    norm_k<<<dim3(2048), blk, 0, stream>>>(g1p0, g1p1, qkv_a, q_a_ln, kv_a_ln,
                                           posid, cosb, sinb, kv_out, cnb, kpe);

    // 3) q = q_a_norm @ q_b_w  AND  kv = c_norm @ kv_b_w  (one dispatch)
    gemm_bt_dual<<<dim3(32, 16, 2), blk, 0, stream>>>(
        qkv_a, qbwt, qbuf, 1536, 2176, 1536, 3072, 24,
        cnb, kvbwt, kvbuf, 512, 512, 512, 4096, 32);

    // 4) fused qrope + value transpose
    post_k<<<dim3(6144), blk, 0, stream>>>(qbuf, posid, cosb, sinb, query, kvbuf, vt);

    // 5) flash attention (4-wave, pipelined, setprio) -> ao bf16 [S][H*128]
    flash_attn<<<dim3(512), dim3(256), 0, stream>>>(query, kvbuf, kpe, vt, ao);

    // 6) out = ao @ o_w (fp32), split-K x2; then out += g5p
    gemm_ks<<<dim3(16, 16, 2), blk, 0, stream>>>(
        ao, owt, g5p, out, 1024, 2048, 2048, 2048);
    addout_k<<<dim3(4096), blk, 0, stream>>>((float4*)out, (const float4*)g5p);
}